// Round 7
// baseline (420.876 us; speedup 1.0000x reference)
//
#include <hip/hip_runtime.h>
#include <hip/hip_bf16.h>
#include <math.h>

// Problem constants (B=1, T=2048)
#define N_TOK 2048
#define C_DIM 1024
#define E_NUM 32
#define TOPKK 4
#define H_EXP 512
#define HS_SH 1024
#define NSLOT (N_TOK * TOPKK)   // 8192

typedef __attribute__((ext_vector_type(8))) short short8;
typedef __attribute__((ext_vector_type(4))) float f32x4;

__device__ __forceinline__ ushort f2b(float f) {
    __hip_bfloat16 h = __float2bfloat16(f);   // RNE
    return *(ushort*)&h;
}
__device__ __forceinline__ float silu_f(float g) { return g / (1.f + __expf(-g)); }

// Direct global->LDS DMA, 16 B per lane. Global src is PER-LANE; LDS dest = uniform base + lane*16.
__device__ __forceinline__ void glds16(const ushort* g, ushort* l) {
    __builtin_amdgcn_global_load_lds(
        (const __attribute__((address_space(1))) unsigned int*)g,
        (__attribute__((address_space(3))) unsigned int*)l, 16, 0, 0);
}

// ---------------- Router: scores + shuffle top-k (no scratch arrays) ----------------
// Also converts this token's x row to bf16 (fuses convert_x).
__global__ __launch_bounds__(256) void router_kernel(
    const float* __restrict__ x, const float* __restrict__ gate_w,
    const float* __restrict__ gate_bias, ushort* __restrict__ xb,
    int* __restrict__ topk_idx, float* __restrict__ topk_w)
{
    __shared__ float xs[C_DIM];
    __shared__ float part[8][E_NUM];
    __shared__ float scores_s[E_NUM];
    const int n = blockIdx.x;
    const int t = threadIdx.x;
    const float* xr = x + (size_t)n * C_DIM;
    {   // load x row + bf16 convert (256 threads * 4 = 1024)
        float4 v = ((const float4*)xr)[t];
        xs[t * 4 + 0] = v.x; xs[t * 4 + 1] = v.y;
        xs[t * 4 + 2] = v.z; xs[t * 4 + 3] = v.w;
        ushort4 o;
        o.x = f2b(v.x); o.y = f2b(v.y); o.z = f2b(v.z); o.w = f2b(v.w);
        ((ushort4*)(xb + (size_t)n * C_DIM))[t] = o;
    }
    __syncthreads();
    const int e = t & 31, cp = t >> 5;
    float s = 0.f;
#pragma unroll 4
    for (int c = cp * 128; c < cp * 128 + 128; ++c)
        s += xs[c] * gate_w[c * E_NUM + e];
    part[cp][e] = s;
    __syncthreads();
    if (t < E_NUM) {
        float tot = 0.f;
#pragma unroll
        for (int i = 0; i < 8; ++i) tot += part[i][t];
        scores_s[t] = 1.f / (1.f + expf(-tot));
    }
    __syncthreads();
    if (t < 64) {   // wave 0: register top-k via shuffle/ballot
        const int l = t;
        const float sc  = (l < E_NUM) ? scores_s[l] : -INFINITY;
        const float scb = (l < E_NUM) ? sc + gate_bias[l] : -INFINITY;
        bool used = false;
        int myidx[TOPKK]; float myw[TOPKK]; float wsum = 0.f;
#pragma unroll
        for (int k = 0; k < TOPKK; ++k) {
            float v = used ? -INFINITY : scb;
            float m = v;
#pragma unroll
            for (int d = 1; d < 64; d <<= 1) m = fmaxf(m, __shfl_xor(m, d));
            unsigned long long b = __ballot(v == m);
            const int pick = __ffsll((unsigned long long)b) - 1;  // lowest index on tie
            if (l == pick) used = true;
            const float w = __shfl(sc, pick);
            myidx[k] = pick; myw[k] = w; wsum += w;
        }
        if (l == 0) {
            const float inv = 1.0f / wsum;   // ROUTE_SCALE = 1.0
#pragma unroll
            for (int k = 0; k < TOPKK; ++k) {
                topk_idx[n * TOPKK + k] = myidx[k];
                topk_w[n * TOPKK + k] = myw[k] * inv;
            }
        }
    }
}

// ---------------- Routing meta: count + scan + scatter, one block ----------------
__global__ __launch_bounds__(1024) void route_build(
    const int* __restrict__ topk_idx, const float* __restrict__ topk_w,
    int* __restrict__ offsets, int* __restrict__ perm_token,
    float* __restrict__ perm_w, int* __restrict__ inv_slot)
{
    __shared__ int cnt[E_NUM];
    __shared__ int off_s[E_NUM + 1];
    const int t = threadIdx.x;
    if (t < E_NUM) cnt[t] = 0;
    __syncthreads();
    int myidx[8];
#pragma unroll
    for (int j = 0; j < 8; ++j) {
        const int i = t * 8 + j;
        myidx[j] = topk_idx[i];
        atomicAdd(&cnt[myidx[j]], 1);
    }
    __syncthreads();
    if (t == 0) {
        int a = 0;
        for (int e2 = 0; e2 < E_NUM; ++e2) { off_s[e2] = a; a += cnt[e2]; }
        off_s[E_NUM] = a;
    }
    __syncthreads();
    if (t < E_NUM) cnt[t] = off_s[t];          // reuse as cursor
    if (t <= E_NUM) offsets[t] = off_s[t];
    __syncthreads();
#pragma unroll
    for (int j = 0; j < 8; ++j) {
        const int i = t * 8 + j;
        const int pos = atomicAdd(&cnt[myidx[j]], 1);
        perm_token[pos] = i >> 2;
        perm_w[pos] = topk_w[i];
        inv_slot[i] = pos;
    }
}

// ---- B reg-stage: fp32 [K][NP] -> bf16 Bs[128][64], fused convert+transpose ----
// Thread t: Bs row c = t&127, k-half h = t>>7. 32 coalesced column loads (lanes =
// consecutive columns, 256B/instr), RNE cvt in reg, 4x ds_write_b128 into the
// SAME swizzled chunk layout the MFMA reads expect (chunk ^= row&7), so the
// GEMM inner loop is unchanged. PAIR_H>0: inverse of the old y/g interleave.
template<int NP, int PAIR_H>
__device__ __forceinline__ void stage_B(const float* __restrict__ W, ushort* Bs,
                                        int n0, int k0, int c, int h)
{
    int gn;
    if (PAIR_H > 0) {
        const int np = n0 + c, lo = np & 31, q = np >> 5;
        gn = (lo < 16) ? q * 16 + lo : PAIR_H + q * 16 + (lo - 16);
    } else {
        gn = n0 + c;
    }
    const float* Wc = W + gn + (size_t)(k0 + h * 32) * NP;
    float v[32];
#pragma unroll
    for (int kk = 0; kk < 32; ++kk)          // all 32 loads issued back-to-back
        v[kk] = Wc[(size_t)kk * NP];
    short8 pk[4];
#pragma unroll
    for (int j = 0; j < 4; ++j)
#pragma unroll
        for (int m = 0; m < 8; ++m) pk[j][m] = (short)f2b(v[j * 8 + m]);
#pragma unroll
    for (int j = 0; j < 4; ++j) {
        const int chunk = (4 * h + j) ^ (c & 7);
        *(short8*)(Bs + c * 64 + chunk * 8) = pk[j];
    }
}

// ---------------- bf16 MFMA GEMM body, 128x128 tile, m97 structure ----------------
// A: glds16 DMA (bf16 activations). B: reg-staged from original fp32 weights
// (transpose kernels eliminated). LDS 32 KB -> 3 blocks/CU preserved.
template<int K, int NP, int PAIR_H, bool EXPERT>
__device__ __forceinline__ void swiglu_body(
    const ushort* __restrict__ Ab, const float* __restrict__ W,
    ushort* __restrict__ Out, const int* __restrict__ offsets,
    const int* __restrict__ perm_tok, int eidx, ushort* S)
{
    constexpr int H = NP / 2;
    int base = 0, cnt = N_TOK;
    const float* Wp = W;
    if (EXPERT) {
        base = offsets[eidx]; cnt = offsets[eidx + 1] - base;
        Wp = W + (size_t)eidx * K * NP;
    }
    const int n0 = blockIdx.x * 128;
    if (n0 >= NP) return;                        // expert path: grid x over-provisioned
    const int m0 = blockIdx.y * 128;
    if (m0 >= cnt) return;
    ushort* O = Out + (size_t)base * H;

    ushort* As = S;
    ushort* Bs = S + 128 * 64;

    const int t = threadIdx.x;
    const int lane = t & 63, wave = t >> 6;
    const int wr = wave >> 1, wc = wave & 1;
    const int quad = lane >> 4, l16 = lane & 15;
    const int srow = lane >> 3;                  // 0..7 within the wave's 8-row group
    const int schunk = (lane & 7) ^ srow;        // swizzled logical 16B-chunk (A DMA)
    const int bc = t & 127, bh = t >> 7;         // B-stage: col, k-half

    f32x4 acc[4][4];
#pragma unroll
    for (int i = 0; i < 4; ++i)
#pragma unroll
        for (int j = 0; j < 4; ++j) acc[i][j] = (f32x4){0.f, 0.f, 0.f, 0.f};

    const ushort* AgI[4];
#pragma unroll
    for (int i = 0; i < 4; ++i) {
        int ar = m0 + wave * 8 + srow + i * 32;
        if (EXPERT) {
            ar = ar < cnt ? ar : 0;
            AgI[i] = Ab + (size_t)perm_tok[base + ar] * K + schunk * 8;
        } else {
            AgI[i] = Ab + (size_t)(base + ar) * K + schunk * 8;
        }
    }

    for (int k0 = 0; k0 < K; k0 += 64) {
        __syncthreads();                         // prev tile reads done
        stage_B<NP, PAIR_H>(Wp, Bs, n0, k0, bc, bh);
#pragma unroll
        for (int i = 0; i < 4; ++i)
            glds16(AgI[i] + k0, As + (wave * 8 + i * 32) * 64);
        __syncthreads();                         // vmcnt(0)+lgkm drain -> tile visible
#pragma unroll
        for (int ks = 0; ks < 2; ++ks) {
            const int coff = (((ks * 4 + quad) ^ (l16 & 7)) << 3);
            short8 af[4], bfr[4];
#pragma unroll
            for (int i = 0; i < 4; ++i) {
                af[i]  = *(const short8*)(As + (wr * 64 + i * 16 + l16) * 64 + coff);
                bfr[i] = *(const short8*)(Bs + (wc * 64 + i * 16 + l16) * 64 + coff);
            }
#pragma unroll
            for (int tm = 0; tm < 4; ++tm)
#pragma unroll
                for (int tn = 0; tn < 4; ++tn)
                    acc[tm][tn] = __builtin_amdgcn_mfma_f32_16x16x32_bf16(
                        af[tm], bfr[tn], acc[tm][tn], 0, 0, 0);
        }
    }

    // Epilogue: SwiGLU pair-combine (tn even=y, odd=g), LDS transpose, 16B stores
    __syncthreads();
#pragma unroll
    for (int tm = 0; tm < 4; ++tm)
#pragma unroll
        for (int p = 0; p < 2; ++p)
#pragma unroll
            for (int r = 0; r < 4; ++r) {
                const int ml = wr * 64 + tm * 16 + quad * 4 + r;
                const int hl = wc * 32 + p * 16 + l16;
                const float y = acc[tm][2 * p][r];
                const float g = acc[tm][2 * p + 1][r];
                S[ml * 72 + hl] = f2b(silu_f(g) * y);    // view as [128][72]
            }
    __syncthreads();
#pragma unroll
    for (int i = 0; i < 4; ++i) {
        const int c = t + i * 256;
        const int row = c >> 3, col = (c & 7) * 8;
        if (m0 + row < cnt)
            *(float4*)(O + (size_t)(m0 + row) * H + (n0 >> 1) + col) =
                *(const float4*)(S + row * 72 + col);
    }
}

template<int K, bool EXPERT>
__device__ __forceinline__ void down_body(
    const ushort* __restrict__ Ab, const float* __restrict__ W,
    float* __restrict__ Out, const int* __restrict__ offsets,
    const float* __restrict__ perm_w, int eidx, ushort* S)
{
    int base = 0, cnt = N_TOK;
    const float* Wp = W;
    if (EXPERT) {
        base = offsets[eidx]; cnt = offsets[eidx + 1] - base;
        Wp = W + (size_t)eidx * K * C_DIM;
    }
    const int m0 = blockIdx.y * 128;
    if (m0 >= cnt) return;
    const int n0 = blockIdx.x * 128;
    const ushort* Ap = Ab + (size_t)base * K;

    ushort* As = S;
    ushort* Bs = S + 128 * 64;

    const int t = threadIdx.x;
    const int lane = t & 63, wave = t >> 6;
    const int wr = wave >> 1, wc = wave & 1;
    const int quad = lane >> 4, l16 = lane & 15;
    const int srow = lane >> 3;
    const int schunk = (lane & 7) ^ srow;
    const int bc = t & 127, bh = t >> 7;

    f32x4 acc[4][4];
#pragma unroll
    for (int i = 0; i < 4; ++i)
#pragma unroll
        for (int j = 0; j < 4; ++j) acc[i][j] = (f32x4){0.f, 0.f, 0.f, 0.f};

    const ushort* Ag = Ap + (size_t)(m0 + wave * 8 + srow) * K + schunk * 8;

    for (int k0 = 0; k0 < K; k0 += 64) {
        __syncthreads();
        stage_B<C_DIM, 0>(Wp, Bs, n0, k0, bc, bh);
#pragma unroll
        for (int i = 0; i < 4; ++i)
            glds16(Ag + (size_t)(i * 32) * K + k0, As + (wave * 8 + i * 32) * 64);
        __syncthreads();
#pragma unroll
        for (int ks = 0; ks < 2; ++ks) {
            const int coff = (((ks * 4 + quad) ^ (l16 & 7)) << 3);
            short8 af[4], bfr[4];
#pragma unroll
            for (int i = 0; i < 4; ++i) {
                af[i]  = *(const short8*)(As + (wr * 64 + i * 16 + l16) * 64 + coff);
                bfr[i] = *(const short8*)(Bs + (wc * 64 + i * 16 + l16) * 64 + coff);
            }
#pragma unroll
            for (int tm = 0; tm < 4; ++tm)
#pragma unroll
                for (int tn = 0; tn < 4; ++tn)
                    acc[tm][tn] = __builtin_amdgcn_mfma_f32_16x16x32_bf16(
                        af[tm], bfr[tn], acc[tm][tn], 0, 0, 0);
        }
    }

#pragma unroll
    for (int tm = 0; tm < 4; ++tm)
#pragma unroll
        for (int r = 0; r < 4; ++r) {
            const int grow = m0 + wr * 64 + tm * 16 + quad * 4 + r;
            if (EXPERT) {
                if (grow < cnt) {
                    const float w = perm_w[base + grow];
#pragma unroll
                    for (int tn = 0; tn < 4; ++tn) {
                        const int col = n0 + wc * 64 + tn * 16 + l16;
                        Out[(size_t)(base + grow) * C_DIM + col] = w * acc[tm][tn][r];
                    }
                }
            } else {
#pragma unroll
                for (int tn = 0; tn < 4; ++tn) {
                    const int col = n0 + wc * 64 + tn * 16 + l16;
                    Out[(size_t)grow * C_DIM + col] = acc[tm][tn][r];
                }
            }
        }
}

// ---------------- Fused GEMM launches: z<32 = experts, z=32 = shared expert ----------------
__global__ __launch_bounds__(256, 3) void swiglu_fused(
    const ushort* __restrict__ xb, const float* __restrict__ sgw,
    const float* __restrict__ egw, ushort* __restrict__ Hs_b,
    ushort* __restrict__ He_b, const int* __restrict__ offsets,
    const int* __restrict__ perm_tok)
{
    __shared__ __align__(16) ushort S[2 * 128 * 64];   // 32 KB, union'd across branches
    const int z = blockIdx.z;
    if (z < E_NUM)
        swiglu_body<C_DIM, 2 * H_EXP, H_EXP, true>(xb, egw, He_b, offsets, perm_tok, z, S);
    else
        swiglu_body<C_DIM, 2 * HS_SH, HS_SH, false>(xb, sgw, Hs_b, nullptr, nullptr, 0, S);
}

__global__ __launch_bounds__(256, 3) void down_fused(
    const ushort* __restrict__ Hs_b, const ushort* __restrict__ He_b,
    const float* __restrict__ sdw, const float* __restrict__ edw,
    float* __restrict__ out, float* __restrict__ Ye,
    const int* __restrict__ offsets, const float* __restrict__ perm_w)
{
    __shared__ __align__(16) ushort S[2 * 128 * 64];
    const int z = blockIdx.z;
    if (z < E_NUM)
        down_body<H_EXP, true>(He_b, edw, Ye, offsets, perm_w, z, S);
    else
        down_body<HS_SH, false>(Hs_b, sdw, out, nullptr, nullptr, 0, S);
}

// out[token] += sum_k Ye[slot_k(token)]   (shared result already in out)
__global__ __launch_bounds__(256) void combine_kernel(
    const float* __restrict__ Ye, const int* __restrict__ inv_slot,
    float* __restrict__ Out)
{
    const int tok = blockIdx.x;
    __shared__ int s4[TOPKK];
    if (threadIdx.x < TOPKK) s4[threadIdx.x] = inv_slot[tok * TOPKK + threadIdx.x];
    __syncthreads();
    const int c = threadIdx.x * 4;
    float4 acc = *(const float4*)(Out + (size_t)tok * C_DIM + c);
#pragma unroll
    for (int k = 0; k < TOPKK; ++k) {
        float4 v = *(const float4*)(Ye + (size_t)s4[k] * C_DIM + c);
        acc.x += v.x; acc.y += v.y; acc.z += v.z; acc.w += v.w;
    }
    *(float4*)(Out + (size_t)tok * C_DIM + c) = acc;
}

extern "C" void kernel_launch(void* const* d_in, const int* in_sizes, int n_in,
                              void* d_out, int out_size, void* d_ws, size_t ws_size,
                              hipStream_t stream)
{
    const float* x   = (const float*)d_in[0];
    const float* gw  = (const float*)d_in[1];
    const float* gb  = (const float*)d_in[2];
    const float* sgw = (const float*)d_in[3];
    const float* sdw = (const float*)d_in[4];
    const float* egw = (const float*)d_in[5];
    const float* edw = (const float*)d_in[6];
    float* out = (float*)d_out;

    char* ws = (char*)d_ws;
    size_t off = 0;
    auto alloc = [&](size_t bytes) -> void* {
        void* p = ws + off;
        off = (off + bytes + 255) & ~(size_t)255;
        return p;
    };
    int*    topk_idx = (int*)   alloc((size_t)NSLOT * sizeof(int));
    float*  topk_w   = (float*) alloc((size_t)NSLOT * sizeof(float));
    int*    offsets  = (int*)   alloc((E_NUM + 1) * sizeof(int));
    int*    perm_tok = (int*)   alloc((size_t)NSLOT * sizeof(int));
    float*  perm_w   = (float*) alloc((size_t)NSLOT * sizeof(float));
    int*    inv_slot = (int*)   alloc((size_t)NSLOT * sizeof(int));
    ushort* xb       = (ushort*)alloc((size_t)N_TOK * C_DIM * 2);
    ushort* Hs_b     = (ushort*)alloc((size_t)N_TOK * HS_SH * 2);
    ushort* He_b     = (ushort*)alloc((size_t)(NSLOT + 128) * H_EXP * 2);
    float*  Ye       = (float*) alloc((size_t)(NSLOT + 128) * C_DIM * sizeof(float));
    (void)ws_size; (void)in_sizes; (void)n_in; (void)out_size;

    // 1) Routing (fp32 scores, shuffle top-k) + fused x->bf16 conversion
    router_kernel<<<N_TOK, 256, 0, stream>>>(x, gw, gb, xb, topk_idx, topk_w);
    // 2) Routing metadata
    route_build<<<1, 1024, 0, stream>>>(topk_idx, topk_w, offsets, perm_tok, perm_w, inv_slot);
    // 3) Shared + expert SwiGLU GEMMs, B reg-staged from fp32 weights (no transposes)
    swiglu_fused<<<dim3(16, N_TOK / 128, E_NUM + 1), 256, 0, stream>>>(
        xb, sgw, egw, Hs_b, He_b, offsets, perm_tok);
    // 4) Shared + expert down GEMMs
    down_fused<<<dim3(C_DIM / 128, N_TOK / 128, E_NUM + 1), 256, 0, stream>>>(
        Hs_b, He_b, sdw, edw, out, Ye, offsets, perm_w);
    // 5) Final combine: out += sum of this token's 4 expert slots
    combine_kernel<<<N_TOK, 256, 0, stream>>>(Ye, inv_slot, out);
}

// Round 8
// 396.032 us; speedup vs baseline: 1.0627x; 1.0627x over previous
//
#include <hip/hip_runtime.h>
#include <hip/hip_bf16.h>
#include <math.h>

// Problem constants (B=1, T=2048)
#define N_TOK 2048
#define C_DIM 1024
#define E_NUM 32
#define TOPKK 4
#define H_EXP 512
#define HS_SH 1024
#define NSLOT (N_TOK * TOPKK)   // 8192

typedef __attribute__((ext_vector_type(8))) short short8;
typedef __attribute__((ext_vector_type(4))) float f32x4;

__device__ __forceinline__ ushort f2b(float f) {
    __hip_bfloat16 h = __float2bfloat16(f);   // RNE
    return *(ushort*)&h;
}
__device__ __forceinline__ float silu_f(float g) { return g / (1.f + __expf(-g)); }

// Direct global->LDS DMA, 16 B per lane. Global src is PER-LANE; LDS dest = uniform base + lane*16.
__device__ __forceinline__ void glds16(const ushort* g, ushort* l) {
    __builtin_amdgcn_global_load_lds(
        (const __attribute__((address_space(1))) unsigned int*)g,
        (__attribute__((address_space(3))) unsigned int*)l, 16, 0, 0);
}

// ---------------- Router body (one block per token) ----------------
// Scores + shuffle top-k; fuses x->bf16 conversion. smem: union'd scratch.
__device__ __forceinline__ void router_body(
    int n, int t, const float* __restrict__ x, const float* __restrict__ gate_w,
    const float* __restrict__ gate_bias, ushort* __restrict__ xb,
    int* __restrict__ topk_idx, float* __restrict__ topk_w, char* smem)
{
    float* xs = (float*)smem;                       // [1024]
    float (*part)[E_NUM] = (float(*)[E_NUM])(smem + 4096);  // [8][32]
    float* scores_s = (float*)(smem + 4096 + 1024); // [32]
    const float* xr = x + (size_t)n * C_DIM;
    {   // load x row + bf16 convert (256 threads * 4 = 1024)
        float4 v = ((const float4*)xr)[t];
        xs[t * 4 + 0] = v.x; xs[t * 4 + 1] = v.y;
        xs[t * 4 + 2] = v.z; xs[t * 4 + 3] = v.w;
        ushort4 o;
        o.x = f2b(v.x); o.y = f2b(v.y); o.z = f2b(v.z); o.w = f2b(v.w);
        ((ushort4*)(xb + (size_t)n * C_DIM))[t] = o;
    }
    __syncthreads();
    const int e = t & 31, cp = t >> 5;
    float s = 0.f;
#pragma unroll 4
    for (int c = cp * 128; c < cp * 128 + 128; ++c)
        s += xs[c] * gate_w[c * E_NUM + e];
    part[cp][e] = s;
    __syncthreads();
    if (t < E_NUM) {
        float tot = 0.f;
#pragma unroll
        for (int i = 0; i < 8; ++i) tot += part[i][t];
        scores_s[t] = 1.f / (1.f + expf(-tot));
    }
    __syncthreads();
    if (t < 64) {   // wave 0: register top-k via shuffle/ballot
        const int l = t;
        const float sc  = (l < E_NUM) ? scores_s[l] : -INFINITY;
        const float scb = (l < E_NUM) ? sc + gate_bias[l] : -INFINITY;
        bool used = false;
        int myidx[TOPKK]; float myw[TOPKK]; float wsum = 0.f;
#pragma unroll
        for (int k = 0; k < TOPKK; ++k) {
            float v = used ? -INFINITY : scb;
            float m = v;
#pragma unroll
            for (int d = 1; d < 64; d <<= 1) m = fmaxf(m, __shfl_xor(m, d));
            unsigned long long b = __ballot(v == m);
            const int pick = __ffsll((unsigned long long)b) - 1;  // lowest index on tie
            if (l == pick) used = true;
            const float w = __shfl(sc, pick);
            myidx[k] = pick; myw[k] = w; wsum += w;
        }
        if (l == 0) {
            const float inv = 1.0f / wsum;   // ROUTE_SCALE = 1.0
#pragma unroll
            for (int k = 0; k < TOPKK; ++k) {
                topk_idx[n * TOPKK + k] = myidx[k];
                topk_w[n * TOPKK + k] = myw[k] * inv;
            }
        }
    }
}

// ---------------- Transpose+convert body, 64(K)x128(N) tile, bf16 LDS ----------------
// ILP=8 (8 float4 loads back-to-back) AND small LDS: convert fp32->bf16 in REGISTERS,
// stage ushort T[64][136] = 17.4 KB (round 6's 33 KB fp32 tile halved occupancy 65->33%
// and erased the ILP win; this keeps ILP at ~2x the occupancy).
// Write: ushort4 8B/lane, lanes span 256B -> 2-way bank alias (free, m136).
// Read: 8x u16 column reads, stride 272B -> 4-way (1.58x, acceptable).
// PAIR_H > 0: interleave y/g in 16-col groups (SwiGLU pairs land adjacent).
template<int K, int N, int PAIR_H>
__device__ __forceinline__ void transp_body(const float* __restrict__ in,
                                            ushort* __restrict__ out,
                                            int bx, int by, int bz, int t, char* smem)
{
    const float* inp = in + (size_t)bz * K * N;
    ushort* outp = out + (size_t)bz * K * N;
    ushort (*T)[136] = (ushort(*)[136])smem;
    const int k0 = by * 64, n0 = bx * 128;
    {
        const int row = t >> 5;          // 0..7
        const int c4  = (t & 31) * 4;    // 0..124
        float4 v[8];
#pragma unroll
        for (int i = 0; i < 8; ++i)      // all 8 loads issued before any use
            v[i] = *(const float4*)(inp + (size_t)(k0 + row + i * 8) * N + n0 + c4);
#pragma unroll
        for (int i = 0; i < 8; ++i) {
            ushort4 o;
            o.x = f2b(v[i].x); o.y = f2b(v[i].y); o.z = f2b(v[i].z); o.w = f2b(v[i].w);
            *(ushort4*)&T[row + i * 8][c4] = o;
        }
    }
    __syncthreads();
    {
        const int g  = t >> 3;           // 0..31: output-row group
        const int kg = t & 7;            // 0..7 : 8-k chunk within the 64-k tile
#pragma unroll
        for (int p = 0; p < 4; ++p) {
            const int nn = p * 32 + g;   // 0..127
            const int gn = n0 + nn;
            int np;
            if (PAIR_H > 0)
                np = (gn < PAIR_H) ? ((gn >> 4) * 32 + (gn & 15))
                                   : (((gn - PAIR_H) >> 4) * 32 + 16 + ((gn - PAIR_H) & 15));
            else
                np = gn;
            short8 o;
#pragma unroll
            for (int j = 0; j < 8; ++j) o[j] = (short)T[kg * 8 + j][nn];
            *(short8*)(outp + (size_t)np * K + k0 + kg * 8) = o;
        }
    }
}

// ---------------- Prep mega-kernel: router + all 4 weight transposes ----------------
// Flat-decoded launch; tasks independent. Tile counts (64k x 128n):
//   sgw 16x16=256 | sdw 8x16=128 | egw 8x16x32=4096 | edw 8x8x32=2048 | router 2048
__global__ __launch_bounds__(256) void prep_mega(
    const float* __restrict__ x, const float* __restrict__ gw,
    const float* __restrict__ gb, const float* __restrict__ sgw,
    const float* __restrict__ sdw, const float* __restrict__ egw,
    const float* __restrict__ edw, ushort* __restrict__ xb,
    int* __restrict__ topk_idx, float* __restrict__ topk_w,
    ushort* __restrict__ sgw_t, ushort* __restrict__ sdw_t,
    ushort* __restrict__ egw_t, ushort* __restrict__ edw_t)
{
    __shared__ __align__(16) char smem[17408];   // union: T[64][136] bf16 / router 5.25 KB
    const int b = blockIdx.x;
    const int t = threadIdx.x;
    if (b < 256) {                       // sgw: (bx 0..15, by 0..15)
        transp_body<C_DIM, 2 * HS_SH, HS_SH>(sgw, sgw_t, b & 15, b >> 4, 0, t, smem);
    } else if (b < 384) {                // sdw: (bx 0..7, by 0..15)
        const int r = b - 256;
        transp_body<HS_SH, C_DIM, 0>(sdw, sdw_t, r & 7, r >> 3, 0, t, smem);
    } else if (b < 4480) {               // egw: (bx 0..7, by 0..15, bz 0..31)
        const int r = b - 384;
        transp_body<C_DIM, 2 * H_EXP, H_EXP>(egw, egw_t, r & 7, (r >> 3) & 15, r >> 7, t, smem);
    } else if (b < 6528) {               // edw: (bx 0..7, by 0..7, bz 0..31)
        const int r = b - 4480;
        transp_body<H_EXP, C_DIM, 0>(edw, edw_t, r & 7, (r >> 3) & 7, r >> 6, t, smem);
    } else {                             // router: 2048 token blocks
        router_body(b - 6528, t, x, gw, gb, xb, topk_idx, topk_w, smem);
    }
}

// ---------------- Routing meta: count + scan + scatter, one block ----------------
__global__ __launch_bounds__(1024) void route_build(
    const int* __restrict__ topk_idx, const float* __restrict__ topk_w,
    int* __restrict__ offsets, int* __restrict__ perm_token,
    float* __restrict__ perm_w, int* __restrict__ inv_slot)
{
    __shared__ int cnt[E_NUM];
    __shared__ int off_s[E_NUM + 1];
    const int t = threadIdx.x;
    if (t < E_NUM) cnt[t] = 0;
    __syncthreads();
    int myidx[8];
#pragma unroll
    for (int j = 0; j < 8; ++j) {
        const int i = t * 8 + j;
        myidx[j] = topk_idx[i];
        atomicAdd(&cnt[myidx[j]], 1);
    }
    __syncthreads();
    if (t == 0) {
        int a = 0;
        for (int e2 = 0; e2 < E_NUM; ++e2) { off_s[e2] = a; a += cnt[e2]; }
        off_s[E_NUM] = a;
    }
    __syncthreads();
    if (t < E_NUM) cnt[t] = off_s[t];          // reuse as cursor
    if (t <= E_NUM) offsets[t] = off_s[t];
    __syncthreads();
#pragma unroll
    for (int j = 0; j < 8; ++j) {
        const int i = t * 8 + j;
        const int pos = atomicAdd(&cnt[myidx[j]], 1);
        perm_token[pos] = i >> 2;
        perm_w[pos] = topk_w[i];
        inv_slot[i] = pos;
    }
}

// ---------------- bf16 MFMA GEMM body, 128x128 tile, m97 structure ----------------
// REVERTED to round-6 form: glds16 DMA both operands from bf16 (the round-7 fp32
// reg-stage collapsed occupancy to 13% and ran every pipe <13% busy).
template<int K, int NP, bool EXPERT>
__device__ __forceinline__ void swiglu_body(
    const ushort* __restrict__ Ab, const ushort* __restrict__ Bt,
    ushort* __restrict__ Out, const int* __restrict__ offsets,
    const int* __restrict__ perm_tok, int eidx, ushort* S)
{
    constexpr int H = NP / 2;
    int base = 0, cnt = N_TOK;
    const ushort* Bp = Bt;
    if (EXPERT) {
        base = offsets[eidx]; cnt = offsets[eidx + 1] - base;
        Bp = Bt + (size_t)eidx * NP * K;
    }
    const int n0 = blockIdx.x * 128;
    if (n0 >= NP) return;                        // expert path: grid x over-provisioned
    const int m0 = blockIdx.y * 128;
    if (m0 >= cnt) return;
    ushort* O = Out + (size_t)base * H;

    ushort* As = S;
    ushort* Bs = S + 128 * 64;

    const int t = threadIdx.x;
    const int lane = t & 63, wave = t >> 6;
    const int wr = wave >> 1, wc = wave & 1;
    const int quad = lane >> 4, l16 = lane & 15;
    const int srow = lane >> 3;                  // 0..7 within the wave's 8-row group
    const int schunk = (lane & 7) ^ srow;        // swizzled logical 16B-chunk

    f32x4 acc[4][4];
#pragma unroll
    for (int i = 0; i < 4; ++i)
#pragma unroll
        for (int j = 0; j < 4; ++j) acc[i][j] = (f32x4){0.f, 0.f, 0.f, 0.f};

    const ushort* AgI[4];
#pragma unroll
    for (int i = 0; i < 4; ++i) {
        int ar = m0 + wave * 8 + srow + i * 32;
        if (EXPERT) {
            ar = ar < cnt ? ar : 0;
            AgI[i] = Ab + (size_t)perm_tok[base + ar] * K + schunk * 8;
        } else {
            AgI[i] = Ab + (size_t)(base + ar) * K + schunk * 8;
        }
    }
    const ushort* Bg = Bp + (size_t)(n0 + wave * 8 + srow) * K + schunk * 8;

    for (int k0 = 0; k0 < K; k0 += 64) {
        __syncthreads();                         // prev tile reads done
#pragma unroll
        for (int i = 0; i < 4; ++i) {
            glds16(AgI[i] + k0, As + (wave * 8 + i * 32) * 64);
            glds16(Bg + (size_t)(i * 32) * K + k0, Bs + (wave * 8 + i * 32) * 64);
        }
        __syncthreads();                         // vmcnt(0) drain -> DMA visible
#pragma unroll
        for (int ks = 0; ks < 2; ++ks) {
            const int coff = (((ks * 4 + quad) ^ (l16 & 7)) << 3);
            short8 af[4], bfr[4];
#pragma unroll
            for (int i = 0; i < 4; ++i) {
                af[i]  = *(const short8*)(As + (wr * 64 + i * 16 + l16) * 64 + coff);
                bfr[i] = *(const short8*)(Bs + (wc * 64 + i * 16 + l16) * 64 + coff);
            }
#pragma unroll
            for (int tm = 0; tm < 4; ++tm)
#pragma unroll
                for (int tn = 0; tn < 4; ++tn)
                    acc[tm][tn] = __builtin_amdgcn_mfma_f32_16x16x32_bf16(
                        af[tm], bfr[tn], acc[tm][tn], 0, 0, 0);
        }
    }

    // Epilogue: SwiGLU pair-combine (tn even=y, odd=g), LDS transpose, 16B stores
    __syncthreads();
#pragma unroll
    for (int tm = 0; tm < 4; ++tm)
#pragma unroll
        for (int p = 0; p < 2; ++p)
#pragma unroll
            for (int r = 0; r < 4; ++r) {
                const int ml = wr * 64 + tm * 16 + quad * 4 + r;
                const int hl = wc * 32 + p * 16 + l16;
                const float y = acc[tm][2 * p][r];
                const float g = acc[tm][2 * p + 1][r];
                S[ml * 72 + hl] = f2b(silu_f(g) * y);    // view as [128][72]
            }
    __syncthreads();
#pragma unroll
    for (int i = 0; i < 4; ++i) {
        const int c = t + i * 256;
        const int row = c >> 3, col = (c & 7) * 8;
        if (m0 + row < cnt)
            *(float4*)(O + (size_t)(m0 + row) * H + (n0 >> 1) + col) =
                *(const float4*)(S + row * 72 + col);
    }
}

template<int K, bool EXPERT>
__device__ __forceinline__ void down_body(
    const ushort* __restrict__ Ab, const ushort* __restrict__ Bt,
    float* __restrict__ Out, const int* __restrict__ offsets,
    const float* __restrict__ perm_w, int eidx, ushort* S)
{
    int base = 0, cnt = N_TOK;
    const ushort* Bp = Bt;
    if (EXPERT) {
        base = offsets[eidx]; cnt = offsets[eidx + 1] - base;
        Bp = Bt + (size_t)eidx * C_DIM * K;
    }
    const int m0 = blockIdx.y * 128;
    if (m0 >= cnt) return;
    const int n0 = blockIdx.x * 128;
    const ushort* Ap = Ab + (size_t)base * K;

    ushort* As = S;
    ushort* Bs = S + 128 * 64;

    const int t = threadIdx.x;
    const int lane = t & 63, wave = t >> 6;
    const int wr = wave >> 1, wc = wave & 1;
    const int quad = lane >> 4, l16 = lane & 15;
    const int srow = lane >> 3;
    const int schunk = (lane & 7) ^ srow;

    f32x4 acc[4][4];
#pragma unroll
    for (int i = 0; i < 4; ++i)
#pragma unroll
        for (int j = 0; j < 4; ++j) acc[i][j] = (f32x4){0.f, 0.f, 0.f, 0.f};

    const ushort* Ag = Ap + (size_t)(m0 + wave * 8 + srow) * K + schunk * 8;
    const ushort* Bg = Bp + (size_t)(n0 + wave * 8 + srow) * K + schunk * 8;

    for (int k0 = 0; k0 < K; k0 += 64) {
        __syncthreads();
#pragma unroll
        for (int i = 0; i < 4; ++i) {
            glds16(Ag + (size_t)(i * 32) * K + k0, As + (wave * 8 + i * 32) * 64);
            glds16(Bg + (size_t)(i * 32) * K + k0, Bs + (wave * 8 + i * 32) * 64);
        }
        __syncthreads();
#pragma unroll
        for (int ks = 0; ks < 2; ++ks) {
            const int coff = (((ks * 4 + quad) ^ (l16 & 7)) << 3);
            short8 af[4], bfr[4];
#pragma unroll
            for (int i = 0; i < 4; ++i) {
                af[i]  = *(const short8*)(As + (wr * 64 + i * 16 + l16) * 64 + coff);
                bfr[i] = *(const short8*)(Bs + (wc * 64 + i * 16 + l16) * 64 + coff);
            }
#pragma unroll
            for (int tm = 0; tm < 4; ++tm)
#pragma unroll
                for (int tn = 0; tn < 4; ++tn)
                    acc[tm][tn] = __builtin_amdgcn_mfma_f32_16x16x32_bf16(
                        af[tm], bfr[tn], acc[tm][tn], 0, 0, 0);
        }
    }

#pragma unroll
    for (int tm = 0; tm < 4; ++tm)
#pragma unroll
        for (int r = 0; r < 4; ++r) {
            const int grow = m0 + wr * 64 + tm * 16 + quad * 4 + r;
            if (EXPERT) {
                if (grow < cnt) {
                    const float w = perm_w[base + grow];
#pragma unroll
                    for (int tn = 0; tn < 4; ++tn) {
                        const int col = n0 + wc * 64 + tn * 16 + l16;
                        Out[(size_t)(base + grow) * C_DIM + col] = w * acc[tm][tn][r];
                    }
                }
            } else {
#pragma unroll
                for (int tn = 0; tn < 4; ++tn) {
                    const int col = n0 + wc * 64 + tn * 16 + l16;
                    Out[(size_t)grow * C_DIM + col] = acc[tm][tn][r];
                }
            }
        }
}

// ---------------- Fused GEMM launches: z<32 = experts, z=32 = shared expert ----------------
__global__ __launch_bounds__(256, 3) void swiglu_fused(
    const ushort* __restrict__ xb, const ushort* __restrict__ sgw_t,
    const ushort* __restrict__ egw_t, ushort* __restrict__ Hs_b,
    ushort* __restrict__ He_b, const int* __restrict__ offsets,
    const int* __restrict__ perm_tok)
{
    __shared__ __align__(16) ushort S[2 * 128 * 64];   // 32 KB, union'd across branches
    const int z = blockIdx.z;
    if (z < E_NUM)
        swiglu_body<C_DIM, 2 * H_EXP, true>(xb, egw_t, He_b, offsets, perm_tok, z, S);
    else
        swiglu_body<C_DIM, 2 * HS_SH, false>(xb, sgw_t, Hs_b, nullptr, nullptr, 0, S);
}

__global__ __launch_bounds__(256, 3) void down_fused(
    const ushort* __restrict__ Hs_b, const ushort* __restrict__ He_b,
    const ushort* __restrict__ sdw_t, const ushort* __restrict__ edw_t,
    float* __restrict__ out, float* __restrict__ Ye,
    const int* __restrict__ offsets, const float* __restrict__ perm_w)
{
    __shared__ __align__(16) ushort S[2 * 128 * 64];
    const int z = blockIdx.z;
    if (z < E_NUM)
        down_body<H_EXP, true>(He_b, edw_t, Ye, offsets, perm_w, z, S);
    else
        down_body<HS_SH, false>(Hs_b, sdw_t, out, nullptr, nullptr, 0, S);
}

// out[token] += sum_k Ye[slot_k(token)]   (shared result already in out)
__global__ __launch_bounds__(256) void combine_kernel(
    const float* __restrict__ Ye, const int* __restrict__ inv_slot,
    float* __restrict__ Out)
{
    const int tok = blockIdx.x;
    __shared__ int s4[TOPKK];
    if (threadIdx.x < TOPKK) s4[threadIdx.x] = inv_slot[tok * TOPKK + threadIdx.x];
    __syncthreads();
    const int c = threadIdx.x * 4;
    float4 acc = *(const float4*)(Out + (size_t)tok * C_DIM + c);
#pragma unroll
    for (int k = 0; k < TOPKK; ++k) {
        float4 v = *(const float4*)(Ye + (size_t)s4[k] * C_DIM + c);
        acc.x += v.x; acc.y += v.y; acc.z += v.z; acc.w += v.w;
    }
    *(float4*)(Out + (size_t)tok * C_DIM + c) = acc;
}

extern "C" void kernel_launch(void* const* d_in, const int* in_sizes, int n_in,
                              void* d_out, int out_size, void* d_ws, size_t ws_size,
                              hipStream_t stream)
{
    const float* x   = (const float*)d_in[0];
    const float* gw  = (const float*)d_in[1];
    const float* gb  = (const float*)d_in[2];
    const float* sgw = (const float*)d_in[3];
    const float* sdw = (const float*)d_in[4];
    const float* egw = (const float*)d_in[5];
    const float* edw = (const float*)d_in[6];
    float* out = (float*)d_out;

    char* ws = (char*)d_ws;
    size_t off = 0;
    auto alloc = [&](size_t bytes) -> void* {
        void* p = ws + off;
        off = (off + bytes + 255) & ~(size_t)255;
        return p;
    };
    int*    topk_idx = (int*)   alloc((size_t)NSLOT * sizeof(int));
    float*  topk_w   = (float*) alloc((size_t)NSLOT * sizeof(float));
    int*    offsets  = (int*)   alloc((E_NUM + 1) * sizeof(int));
    int*    perm_tok = (int*)   alloc((size_t)NSLOT * sizeof(int));
    float*  perm_w   = (float*) alloc((size_t)NSLOT * sizeof(float));
    int*    inv_slot = (int*)   alloc((size_t)NSLOT * sizeof(int));
    ushort* xb       = (ushort*)alloc((size_t)N_TOK * C_DIM * 2);
    ushort* sgw_t    = (ushort*)alloc((size_t)C_DIM * 2 * HS_SH * 2);
    ushort* sdw_t    = (ushort*)alloc((size_t)HS_SH * C_DIM * 2);
    ushort* egw_t    = (ushort*)alloc((size_t)E_NUM * C_DIM * 2 * H_EXP * 2);
    ushort* edw_t    = (ushort*)alloc((size_t)E_NUM * H_EXP * C_DIM * 2);
    ushort* Hs_b     = (ushort*)alloc((size_t)N_TOK * HS_SH * 2);
    ushort* He_b     = (ushort*)alloc((size_t)(NSLOT + 128) * H_EXP * 2);
    float*  Ye       = (float*) alloc((size_t)(NSLOT + 128) * C_DIM * sizeof(float));
    (void)ws_size; (void)in_sizes; (void)n_in; (void)out_size;

    // 1) Router + all weight transposes (independent) in one flat launch
    //    blocks: sgw 256 | sdw 128 | egw 4096 | edw 2048 | router 2048 = 8576
    prep_mega<<<8576, 256, 0, stream>>>(x, gw, gb, sgw, sdw, egw, edw,
                                        xb, topk_idx, topk_w,
                                        sgw_t, sdw_t, egw_t, edw_t);
    // 2) Routing metadata
    route_build<<<1, 1024, 0, stream>>>(topk_idx, topk_w, offsets, perm_tok, perm_w, inv_slot);
    // 3) Shared + expert SwiGLU GEMMs in one launch (z: 0..31 experts, 32 shared)
    swiglu_fused<<<dim3(16, N_TOK / 128, E_NUM + 1), 256, 0, stream>>>(
        xb, sgw_t, egw_t, Hs_b, He_b, offsets, perm_tok);
    // 4) Shared + expert down GEMMs in one launch
    down_fused<<<dim3(C_DIM / 128, N_TOK / 128, E_NUM + 1), 256, 0, stream>>>(
        Hs_b, He_b, sdw_t, edw_t, out, Ye, offsets, perm_w);
    // 5) Final combine: out += sum of this token's 4 expert slots
    combine_kernel<<<N_TOK, 256, 0, stream>>>(Ye, inv_slot, out);
}

// Round 10
// 379.594 us; speedup vs baseline: 1.1088x; 1.0433x over previous
//
#include <hip/hip_runtime.h>
#include <hip/hip_bf16.h>
#include <math.h>

// Problem constants (B=1, T=2048)
#define N_TOK 2048
#define C_DIM 1024
#define E_NUM 32
#define TOPKK 4
#define H_EXP 512
#define HS_SH 1024
#define NSLOT (N_TOK * TOPKK)   // 8192

typedef __attribute__((ext_vector_type(8))) short short8;
typedef __attribute__((ext_vector_type(4))) float f32x4;

__device__ __forceinline__ ushort f2b(float f) {
    __hip_bfloat16 h = __float2bfloat16(f);   // RNE
    return *(ushort*)&h;
}
__device__ __forceinline__ float silu_f(float g) { return g / (1.f + __expf(-g)); }

// Direct global->LDS DMA, 16 B per lane. Global src is PER-LANE; LDS dest = uniform base + lane*16.
__device__ __forceinline__ void glds16(const ushort* g, ushort* l) {
    __builtin_amdgcn_global_load_lds(
        (const __attribute__((address_space(1))) unsigned int*)g,
        (__attribute__((address_space(3))) unsigned int*)l, 16, 0, 0);
}

// ---------------- Router body (one block per token) ----------------
// Scores + shuffle top-k; fuses x->bf16 conversion. smem: union'd scratch.
__device__ __forceinline__ void router_body(
    int n, int t, const float* __restrict__ x, const float* __restrict__ gate_w,
    const float* __restrict__ gate_bias, ushort* __restrict__ xb,
    int* __restrict__ topk_idx, float* __restrict__ topk_w, char* smem)
{
    float* xs = (float*)smem;                       // [1024]
    float (*part)[E_NUM] = (float(*)[E_NUM])(smem + 4096);  // [8][32]
    float* scores_s = (float*)(smem + 4096 + 1024); // [32]
    const float* xr = x + (size_t)n * C_DIM;
    {   // load x row + bf16 convert (256 threads * 4 = 1024)
        float4 v = ((const float4*)xr)[t];
        xs[t * 4 + 0] = v.x; xs[t * 4 + 1] = v.y;
        xs[t * 4 + 2] = v.z; xs[t * 4 + 3] = v.w;
        ushort4 o;
        o.x = f2b(v.x); o.y = f2b(v.y); o.z = f2b(v.z); o.w = f2b(v.w);
        ((ushort4*)(xb + (size_t)n * C_DIM))[t] = o;
    }
    __syncthreads();
    const int e = t & 31, cp = t >> 5;
    float s = 0.f;
#pragma unroll 4
    for (int c = cp * 128; c < cp * 128 + 128; ++c)
        s += xs[c] * gate_w[c * E_NUM + e];
    part[cp][e] = s;
    __syncthreads();
    if (t < E_NUM) {
        float tot = 0.f;
#pragma unroll
        for (int i = 0; i < 8; ++i) tot += part[i][t];
        scores_s[t] = 1.f / (1.f + expf(-tot));
    }
    __syncthreads();
    if (t < 64) {   // wave 0: register top-k via shuffle/ballot
        const int l = t;
        const float sc  = (l < E_NUM) ? scores_s[l] : -INFINITY;
        const float scb = (l < E_NUM) ? sc + gate_bias[l] : -INFINITY;
        bool used = false;
        int myidx[TOPKK]; float myw[TOPKK]; float wsum = 0.f;
#pragma unroll
        for (int k = 0; k < TOPKK; ++k) {
            float v = used ? -INFINITY : scb;
            float m = v;
#pragma unroll
            for (int d = 1; d < 64; d <<= 1) m = fmaxf(m, __shfl_xor(m, d));
            unsigned long long b = __ballot(v == m);
            const int pick = __ffsll((unsigned long long)b) - 1;  // lowest index on tie
            if (l == pick) used = true;
            const float w = __shfl(sc, pick);
            myidx[k] = pick; myw[k] = w; wsum += w;
        }
        if (l == 0) {
            const float inv = 1.0f / wsum;   // ROUTE_SCALE = 1.0
#pragma unroll
            for (int k = 0; k < TOPKK; ++k) {
                topk_idx[n * TOPKK + k] = myidx[k];
                topk_w[n * TOPKK + k] = myw[k] * inv;
            }
        }
    }
}

// ---------------- Transpose+convert body, 64(K)x128(N) tile, bf16 LDS ----------------
// ILP=8 (8 float4 loads back-to-back), bf16 T[64][132] = 16.9 KB, XOR-swizzled
// columns: col' = col ^ ((row>>3)<<2). Bank math ([132] -> 66 dw, 66%32=2):
//   read  (u16 col-reads): bank = 16(kg&1)+2j + ((nn^(kg<<2))>>1) -> all 32 banks,
//         same-dword u16 pairs broadcast -> conflict-free (round-8's [136] was ~16-way).
//   write (ushort4): row parity separates banks -> 2-way (free, m136).
// PAIR_H > 0: interleave y/g in 16-col groups (SwiGLU pairs land adjacent).
template<int K, int N, int PAIR_H>
__device__ __forceinline__ void transp_body(const float* __restrict__ in,
                                            ushort* __restrict__ out,
                                            int bx, int by, int bz, int t, char* smem)
{
    const float* inp = in + (size_t)bz * K * N;
    ushort* outp = out + (size_t)bz * K * N;
    ushort (*T)[132] = (ushort(*)[132])smem;
    const int k0 = by * 64, n0 = bx * 128;
    {
        const int rr = t >> 5;           // 0..7
        const int c4 = (t & 31) * 4;     // 0..124
        float4 v[8];
#pragma unroll
        for (int i = 0; i < 8; ++i)      // all 8 loads issued before any use
            v[i] = *(const float4*)(inp + (size_t)(k0 + rr + i * 8) * N + n0 + c4);
#pragma unroll
        for (int i = 0; i < 8; ++i) {
            const int row = rr + i * 8;
            ushort4 o;
            o.x = f2b(v[i].x); o.y = f2b(v[i].y); o.z = f2b(v[i].z); o.w = f2b(v[i].w);
            *(ushort4*)&T[row][c4 ^ ((row >> 3) << 2)] = o;
        }
    }
    __syncthreads();
    {
        const int g  = t >> 3;           // 0..31: output-row group
        const int kg = t & 7;            // 0..7 : 8-k chunk within the 64-k tile
#pragma unroll
        for (int p = 0; p < 4; ++p) {
            const int nn = p * 32 + g;   // 0..127
            const int nsw = nn ^ (kg << 2);
            const int gn = n0 + nn;
            int np;
            if (PAIR_H > 0)
                np = (gn < PAIR_H) ? ((gn >> 4) * 32 + (gn & 15))
                                   : (((gn - PAIR_H) >> 4) * 32 + 16 + ((gn - PAIR_H) & 15));
            else
                np = gn;
            short8 o;
#pragma unroll
            for (int j = 0; j < 8; ++j) o[j] = (short)T[kg * 8 + j][nsw];
            *(short8*)(outp + (size_t)np * K + k0 + kg * 8) = o;
        }
    }
}

// ---------------- Prep mega-kernel: router + sgw/egw transposes ----------------
// sdw/edw transposes moved into swiglu_fused's launch (they only feed down_fused,
// and their memory-only blocks overlap with swiglu's MFMA phases there).
//   sgw 16x16=256 | egw 8x16x32=4096 | router 2048  -> 6400 blocks
__global__ __launch_bounds__(256) void prep_mega(
    const float* __restrict__ x, const float* __restrict__ gw,
    const float* __restrict__ gb, const float* __restrict__ sgw,
    const float* __restrict__ egw, ushort* __restrict__ xb,
    int* __restrict__ topk_idx, float* __restrict__ topk_w,
    ushort* __restrict__ sgw_t, ushort* __restrict__ egw_t)
{
    __shared__ __align__(16) char smem[16896];   // union: T[64][132] bf16 / router 5.25 KB
    const int b = blockIdx.x;
    const int t = threadIdx.x;
    if (b < 256) {                       // sgw: (bx 0..15, by 0..15)
        transp_body<C_DIM, 2 * HS_SH, HS_SH>(sgw, sgw_t, b & 15, b >> 4, 0, t, smem);
    } else if (b < 4352) {               // egw: (bx 0..7, by 0..15, bz 0..31)
        const int r = b - 256;
        transp_body<C_DIM, 2 * H_EXP, H_EXP>(egw, egw_t, r & 7, (r >> 3) & 15, r >> 7, t, smem);
    } else {                             // router: 2048 token blocks
        router_body(b - 4352, t, x, gw, gb, xb, topk_idx, topk_w, smem);
    }
}

// ---------------- Routing meta: count + scan + scatter, one block ----------------
__global__ __launch_bounds__(1024) void route_build(
    const int* __restrict__ topk_idx, const float* __restrict__ topk_w,
    int* __restrict__ offsets, int* __restrict__ perm_token,
    float* __restrict__ perm_w, int* __restrict__ inv_slot)
{
    __shared__ int cnt[E_NUM];
    __shared__ int off_s[E_NUM + 1];
    const int t = threadIdx.x;
    if (t < E_NUM) cnt[t] = 0;
    __syncthreads();
    int myidx[8];
#pragma unroll
    for (int j = 0; j < 8; ++j) {
        const int i = t * 8 + j;
        myidx[j] = topk_idx[i];
        atomicAdd(&cnt[myidx[j]], 1);
    }
    __syncthreads();
    if (t == 0) {
        int a = 0;
        for (int e2 = 0; e2 < E_NUM; ++e2) { off_s[e2] = a; a += cnt[e2]; }
        off_s[E_NUM] = a;
    }
    __syncthreads();
    if (t < E_NUM) cnt[t] = off_s[t];          // reuse as cursor
    if (t <= E_NUM) offsets[t] = off_s[t];
    __syncthreads();
#pragma unroll
    for (int j = 0; j < 8; ++j) {
        const int i = t * 8 + j;
        const int pos = atomicAdd(&cnt[myidx[j]], 1);
        perm_token[pos] = i >> 2;
        perm_w[pos] = topk_w[i];
        inv_slot[i] = pos;
    }
}

// ---------------- bf16 MFMA GEMM body, 128x128 tile, m97 structure ----------------
template<int K, int NP, bool EXPERT>
__device__ __forceinline__ void swiglu_body(
    const ushort* __restrict__ Ab, const ushort* __restrict__ Bt,
    ushort* __restrict__ Out, const int* __restrict__ offsets,
    const int* __restrict__ perm_tok, int eidx, ushort* S)
{
    constexpr int H = NP / 2;
    int base = 0, cnt = N_TOK;
    const ushort* Bp = Bt;
    if (EXPERT) {
        base = offsets[eidx]; cnt = offsets[eidx + 1] - base;
        Bp = Bt + (size_t)eidx * NP * K;
    }
    const int n0 = blockIdx.x * 128;
    if (n0 >= NP) return;                        // expert path: grid x over-provisioned
    const int m0 = blockIdx.y * 128;
    if (m0 >= cnt) return;
    ushort* O = Out + (size_t)base * H;

    ushort* As = S;
    ushort* Bs = S + 128 * 64;

    const int t = threadIdx.x;
    const int lane = t & 63, wave = t >> 6;
    const int wr = wave >> 1, wc = wave & 1;
    const int quad = lane >> 4, l16 = lane & 15;
    const int srow = lane >> 3;                  // 0..7 within the wave's 8-row group
    const int schunk = (lane & 7) ^ srow;        // swizzled logical 16B-chunk

    f32x4 acc[4][4];
#pragma unroll
    for (int i = 0; i < 4; ++i)
#pragma unroll
        for (int j = 0; j < 4; ++j) acc[i][j] = (f32x4){0.f, 0.f, 0.f, 0.f};

    const ushort* AgI[4];
#pragma unroll
    for (int i = 0; i < 4; ++i) {
        int ar = m0 + wave * 8 + srow + i * 32;
        if (EXPERT) {
            ar = ar < cnt ? ar : 0;
            AgI[i] = Ab + (size_t)perm_tok[base + ar] * K + schunk * 8;
        } else {
            AgI[i] = Ab + (size_t)(base + ar) * K + schunk * 8;
        }
    }
    const ushort* Bg = Bp + (size_t)(n0 + wave * 8 + srow) * K + schunk * 8;

    for (int k0 = 0; k0 < K; k0 += 64) {
        __syncthreads();                         // prev tile reads done
#pragma unroll
        for (int i = 0; i < 4; ++i) {
            glds16(AgI[i] + k0, As + (wave * 8 + i * 32) * 64);
            glds16(Bg + (size_t)(i * 32) * K + k0, Bs + (wave * 8 + i * 32) * 64);
        }
        __syncthreads();                         // vmcnt(0) drain -> DMA visible
#pragma unroll
        for (int ks = 0; ks < 2; ++ks) {
            const int coff = (((ks * 4 + quad) ^ (l16 & 7)) << 3);
            short8 af[4], bfr[4];
#pragma unroll
            for (int i = 0; i < 4; ++i) {
                af[i]  = *(const short8*)(As + (wr * 64 + i * 16 + l16) * 64 + coff);
                bfr[i] = *(const short8*)(Bs + (wc * 64 + i * 16 + l16) * 64 + coff);
            }
#pragma unroll
            for (int tm = 0; tm < 4; ++tm)
#pragma unroll
                for (int tn = 0; tn < 4; ++tn)
                    acc[tm][tn] = __builtin_amdgcn_mfma_f32_16x16x32_bf16(
                        af[tm], bfr[tn], acc[tm][tn], 0, 0, 0);
        }
    }

    // Epilogue: SwiGLU pair-combine (tn even=y, odd=g), LDS transpose, 16B stores
    __syncthreads();
#pragma unroll
    for (int tm = 0; tm < 4; ++tm)
#pragma unroll
        for (int p = 0; p < 2; ++p)
#pragma unroll
            for (int r = 0; r < 4; ++r) {
                const int ml = wr * 64 + tm * 16 + quad * 4 + r;
                const int hl = wc * 32 + p * 16 + l16;
                const float y = acc[tm][2 * p][r];
                const float g = acc[tm][2 * p + 1][r];
                S[ml * 72 + hl] = f2b(silu_f(g) * y);    // view as [128][72]
            }
    __syncthreads();
#pragma unroll
    for (int i = 0; i < 4; ++i) {
        const int c = t + i * 256;
        const int row = c >> 3, col = (c & 7) * 8;
        if (m0 + row < cnt)
            *(float4*)(O + (size_t)(m0 + row) * H + (n0 >> 1) + col) =
                *(const float4*)(S + row * 72 + col);
    }
}

template<int K, bool EXPERT>
__device__ __forceinline__ void down_body(
    const ushort* __restrict__ Ab, const ushort* __restrict__ Bt,
    float* __restrict__ Out, const int* __restrict__ offsets,
    const float* __restrict__ perm_w, int eidx, ushort* S)
{
    int base = 0, cnt = N_TOK;
    const ushort* Bp = Bt;
    if (EXPERT) {
        base = offsets[eidx]; cnt = offsets[eidx + 1] - base;
        Bp = Bt + (size_t)eidx * C_DIM * K;
    }
    const int m0 = blockIdx.y * 128;
    if (m0 >= cnt) return;
    const int n0 = blockIdx.x * 128;
    const ushort* Ap = Ab + (size_t)base * K;

    ushort* As = S;
    ushort* Bs = S + 128 * 64;

    const int t = threadIdx.x;
    const int lane = t & 63, wave = t >> 6;
    const int wr = wave >> 1, wc = wave & 1;
    const int quad = lane >> 4, l16 = lane & 15;
    const int srow = lane >> 3;
    const int schunk = (lane & 7) ^ srow;

    f32x4 acc[4][4];
#pragma unroll
    for (int i = 0; i < 4; ++i)
#pragma unroll
        for (int j = 0; j < 4; ++j) acc[i][j] = (f32x4){0.f, 0.f, 0.f, 0.f};

    const ushort* Ag = Ap + (size_t)(m0 + wave * 8 + srow) * K + schunk * 8;
    const ushort* Bg = Bp + (size_t)(n0 + wave * 8 + srow) * K + schunk * 8;

    for (int k0 = 0; k0 < K; k0 += 64) {
        __syncthreads();
#pragma unroll
        for (int i = 0; i < 4; ++i) {
            glds16(Ag + (size_t)(i * 32) * K + k0, As + (wave * 8 + i * 32) * 64);
            glds16(Bg + (size_t)(i * 32) * K + k0, Bs + (wave * 8 + i * 32) * 64);
        }
        __syncthreads();
#pragma unroll
        for (int ks = 0; ks < 2; ++ks) {
            const int coff = (((ks * 4 + quad) ^ (l16 & 7)) << 3);
            short8 af[4], bfr[4];
#pragma unroll
            for (int i = 0; i < 4; ++i) {
                af[i]  = *(const short8*)(As + (wr * 64 + i * 16 + l16) * 64 + coff);
                bfr[i] = *(const short8*)(Bs + (wc * 64 + i * 16 + l16) * 64 + coff);
            }
#pragma unroll
            for (int tm = 0; tm < 4; ++tm)
#pragma unroll
                for (int tn = 0; tn < 4; ++tn)
                    acc[tm][tn] = __builtin_amdgcn_mfma_f32_16x16x32_bf16(
                        af[tm], bfr[tn], acc[tm][tn], 0, 0, 0);
        }
    }

#pragma unroll
    for (int tm = 0; tm < 4; ++tm)
#pragma unroll
        for (int r = 0; r < 4; ++r) {
            const int grow = m0 + wr * 64 + tm * 16 + quad * 4 + r;
            if (EXPERT) {
                if (grow < cnt) {
                    const float w = perm_w[base + grow];
#pragma unroll
                    for (int tn = 0; tn < 4; ++tn) {
                        const int col = n0 + wc * 64 + tn * 16 + l16;
                        Out[(size_t)(base + grow) * C_DIM + col] = w * acc[tm][tn][r];
                    }
                }
            } else {
#pragma unroll
                for (int tn = 0; tn < 4; ++tn) {
                    const int col = n0 + wc * 64 + tn * 16 + l16;
                    Out[(size_t)grow * C_DIM + col] = acc[tm][tn][r];
                }
            }
        }
}

// ---------------- Fused SwiGLU launch ----------------
// z<32: expert GEMMs; z=32: shared GEMM; z>=33: sdw/edw transposes (memory-only
// blocks riding along to overlap with the GEMM's MFMA phases; they only feed
// down_fused, so launch-order dependency suffices).
__global__ __launch_bounds__(256, 3) void swiglu_fused(
    const ushort* __restrict__ xb, const ushort* __restrict__ sgw_t,
    const ushort* __restrict__ egw_t, ushort* __restrict__ Hs_b,
    ushort* __restrict__ He_b, const int* __restrict__ offsets,
    const int* __restrict__ perm_tok,
    const float* __restrict__ sdw, const float* __restrict__ edw,
    ushort* __restrict__ sdw_t, ushort* __restrict__ edw_t)
{
    __shared__ __align__(16) ushort S[2 * 128 * 64];   // 32 KB, union'd across branches
    const int z = blockIdx.z;
    if (z >= 33) {                                     // transpose planes
        const int flat = (z - 33) * 256 + blockIdx.y * 16 + blockIdx.x;
        if (flat < 128) {                              // sdw: (bx 0..7, by 0..15)
            transp_body<HS_SH, C_DIM, 0>(sdw, sdw_t, flat & 7, flat >> 3, 0,
                                         threadIdx.x, (char*)S);
        } else if (flat < 2176) {                      // edw: (bx 0..7, by 0..7, bz 0..31)
            const int r = flat - 128;
            transp_body<H_EXP, C_DIM, 0>(edw, edw_t, r & 7, (r >> 3) & 7, r >> 6,
                                         threadIdx.x, (char*)S);
        }
        return;
    }
    if (z < E_NUM)
        swiglu_body<C_DIM, 2 * H_EXP, true>(xb, egw_t, He_b, offsets, perm_tok, z, S);
    else
        swiglu_body<C_DIM, 2 * HS_SH, false>(xb, sgw_t, Hs_b, nullptr, nullptr, 0, S);
}

__global__ __launch_bounds__(256, 3) void down_fused(
    const ushort* __restrict__ Hs_b, const ushort* __restrict__ He_b,
    const ushort* __restrict__ sdw_t, const ushort* __restrict__ edw_t,
    float* __restrict__ out, float* __restrict__ Ye,
    const int* __restrict__ offsets, const float* __restrict__ perm_w)
{
    __shared__ __align__(16) ushort S[2 * 128 * 64];
    const int z = blockIdx.z;
    if (z < E_NUM)
        down_body<H_EXP, true>(He_b, edw_t, Ye, offsets, perm_w, z, S);
    else
        down_body<HS_SH, false>(Hs_b, sdw_t, out, nullptr, nullptr, 0, S);
}

// out[token] += sum_k Ye[slot_k(token)]   (shared result already in out)
__global__ __launch_bounds__(256) void combine_kernel(
    const float* __restrict__ Ye, const int* __restrict__ inv_slot,
    float* __restrict__ Out)
{
    const int tok = blockIdx.x;
    __shared__ int s4[TOPKK];
    if (threadIdx.x < TOPKK) s4[threadIdx.x] = inv_slot[tok * TOPKK + threadIdx.x];
    __syncthreads();
    const int c = threadIdx.x * 4;
    float4 acc = *(const float4*)(Out + (size_t)tok * C_DIM + c);
#pragma unroll
    for (int k = 0; k < TOPKK; ++k) {
        float4 v = *(const float4*)(Ye + (size_t)s4[k] * C_DIM + c);
        acc.x += v.x; acc.y += v.y; acc.z += v.z; acc.w += v.w;
    }
    *(float4*)(Out + (size_t)tok * C_DIM + c) = acc;
}

extern "C" void kernel_launch(void* const* d_in, const int* in_sizes, int n_in,
                              void* d_out, int out_size, void* d_ws, size_t ws_size,
                              hipStream_t stream)
{
    const float* x   = (const float*)d_in[0];
    const float* gw  = (const float*)d_in[1];
    const float* gb  = (const float*)d_in[2];
    const float* sgw = (const float*)d_in[3];
    const float* sdw = (const float*)d_in[4];
    const float* egw = (const float*)d_in[5];
    const float* edw = (const float*)d_in[6];
    float* out = (float*)d_out;

    char* ws = (char*)d_ws;
    size_t off = 0;
    auto alloc = [&](size_t bytes) -> void* {
        void* p = ws + off;
        off = (off + bytes + 255) & ~(size_t)255;
        return p;
    };
    int*    topk_idx = (int*)   alloc((size_t)NSLOT * sizeof(int));
    float*  topk_w   = (float*) alloc((size_t)NSLOT * sizeof(float));
    int*    offsets  = (int*)   alloc((E_NUM + 1) * sizeof(int));
    int*    perm_tok = (int*)   alloc((size_t)NSLOT * sizeof(int));
    float*  perm_w   = (float*) alloc((size_t)NSLOT * sizeof(float));
    int*    inv_slot = (int*)   alloc((size_t)NSLOT * sizeof(int));
    ushort* xb       = (ushort*)alloc((size_t)N_TOK * C_DIM * 2);
    ushort* sgw_t    = (ushort*)alloc((size_t)C_DIM * 2 * HS_SH * 2);
    ushort* sdw_t    = (ushort*)alloc((size_t)HS_SH * C_DIM * 2);
    ushort* egw_t    = (ushort*)alloc((size_t)E_NUM * C_DIM * 2 * H_EXP * 2);
    ushort* edw_t    = (ushort*)alloc((size_t)E_NUM * H_EXP * C_DIM * 2);
    ushort* Hs_b     = (ushort*)alloc((size_t)N_TOK * HS_SH * 2);
    ushort* He_b     = (ushort*)alloc((size_t)(NSLOT + 128) * H_EXP * 2);
    float*  Ye       = (float*) alloc((size_t)(NSLOT + 128) * C_DIM * sizeof(float));
    (void)ws_size; (void)in_sizes; (void)n_in; (void)out_size;

    // 1) Router + sgw/egw transposes: sgw 256 | egw 4096 | router 2048 = 6400 blocks
    prep_mega<<<6400, 256, 0, stream>>>(x, gw, gb, sgw, egw,
                                        xb, topk_idx, topk_w, sgw_t, egw_t);
    // 2) Routing metadata
    route_build<<<1, 1024, 0, stream>>>(topk_idx, topk_w, offsets, perm_tok, perm_w, inv_slot);
    // 3) SwiGLU GEMMs (z 0..31 experts, 32 shared) + sdw/edw transposes (z 33..41)
    swiglu_fused<<<dim3(16, N_TOK / 128, 42), 256, 0, stream>>>(
        xb, sgw_t, egw_t, Hs_b, He_b, offsets, perm_tok, sdw, edw, sdw_t, edw_t);
    // 4) Shared + expert down GEMMs
    down_fused<<<dim3(C_DIM / 128, N_TOK / 128, E_NUM + 1), 256, 0, stream>>>(
        Hs_b, He_b, sdw_t, edw_t, out, Ye, offsets, perm_w);
    // 5) Final combine: out += sum of this token's 4 expert slots
    combine_kernel<<<N_TOK, 256, 0, stream>>>(Ye, inv_slot, out);
}

// Round 11
// 354.171 us; speedup vs baseline: 1.1883x; 1.0718x over previous
//
#include <hip/hip_runtime.h>
#include <hip/hip_bf16.h>
#include <math.h>

// Problem constants (B=1, T=2048)
#define N_TOK 2048
#define C_DIM 1024
#define E_NUM 32
#define TOPKK 4
#define H_EXP 512
#define HS_SH 1024
#define NSLOT (N_TOK * TOPKK)   // 8192

typedef __attribute__((ext_vector_type(8))) short short8;
typedef __attribute__((ext_vector_type(4))) float f32x4;

__device__ __forceinline__ ushort f2b(float f) {
    __hip_bfloat16 h = __float2bfloat16(f);   // RNE
    return *(ushort*)&h;
}
__device__ __forceinline__ float silu_f(float g) { return g / (1.f + __expf(-g)); }

// Direct global->LDS DMA, 16 B per lane. Global src is PER-LANE; LDS dest = uniform base + lane*16.
__device__ __forceinline__ void glds16(const ushort* g, ushort* l) {
    __builtin_amdgcn_global_load_lds(
        (const __attribute__((address_space(1))) unsigned int*)g,
        (__attribute__((address_space(3))) unsigned int*)l, 16, 0, 0);
}

// ---------------- Router body (one block per token) ----------------
__device__ __forceinline__ void router_body(
    int n, int t, const float* __restrict__ x, const float* __restrict__ gate_w,
    const float* __restrict__ gate_bias, ushort* __restrict__ xb,
    int* __restrict__ topk_idx, float* __restrict__ topk_w, char* smem)
{
    float* xs = (float*)smem;                       // [1024]
    float (*part)[E_NUM] = (float(*)[E_NUM])(smem + 4096);  // [8][32]
    float* scores_s = (float*)(smem + 4096 + 1024); // [32]
    const float* xr = x + (size_t)n * C_DIM;
    {   // load x row + bf16 convert (256 threads * 4 = 1024)
        float4 v = ((const float4*)xr)[t];
        xs[t * 4 + 0] = v.x; xs[t * 4 + 1] = v.y;
        xs[t * 4 + 2] = v.z; xs[t * 4 + 3] = v.w;
        ushort4 o;
        o.x = f2b(v.x); o.y = f2b(v.y); o.z = f2b(v.z); o.w = f2b(v.w);
        ((ushort4*)(xb + (size_t)n * C_DIM))[t] = o;
    }
    __syncthreads();
    const int e = t & 31, cp = t >> 5;
    float s = 0.f;
#pragma unroll 4
    for (int c = cp * 128; c < cp * 128 + 128; ++c)
        s += xs[c] * gate_w[c * E_NUM + e];
    part[cp][e] = s;
    __syncthreads();
    if (t < E_NUM) {
        float tot = 0.f;
#pragma unroll
        for (int i = 0; i < 8; ++i) tot += part[i][t];
        scores_s[t] = 1.f / (1.f + expf(-tot));
    }
    __syncthreads();
    if (t < 64) {   // wave 0: register top-k via shuffle/ballot
        const int l = t;
        const float sc  = (l < E_NUM) ? scores_s[l] : -INFINITY;
        const float scb = (l < E_NUM) ? sc + gate_bias[l] : -INFINITY;
        bool used = false;
        int myidx[TOPKK]; float myw[TOPKK]; float wsum = 0.f;
#pragma unroll
        for (int k = 0; k < TOPKK; ++k) {
            float v = used ? -INFINITY : scb;
            float m = v;
#pragma unroll
            for (int d = 1; d < 64; d <<= 1) m = fmaxf(m, __shfl_xor(m, d));
            unsigned long long b = __ballot(v == m);
            const int pick = __ffsll((unsigned long long)b) - 1;  // lowest index on tie
            if (l == pick) used = true;
            const float w = __shfl(sc, pick);
            myidx[k] = pick; myw[k] = w; wsum += w;
        }
        if (l == 0) {
            const float inv = 1.0f / wsum;   // ROUTE_SCALE = 1.0
#pragma unroll
            for (int k = 0; k < TOPKK; ++k) {
                topk_idx[n * TOPKK + k] = myidx[k];
                topk_w[n * TOPKK + k] = myw[k] * inv;
            }
        }
    }
}

// ---------------- Transpose+convert body, 64(K)x128(N) tile, bf16 LDS ----------------
// ILP=8, bf16 T[64][132] = 16.9 KB, XOR-swizzled cols (r10: bank conflicts 11.7M -> 0).
template<int K, int N, int PAIR_H>
__device__ __forceinline__ void transp_body(const float* __restrict__ in,
                                            ushort* __restrict__ out,
                                            int bx, int by, int bz, int t, char* smem)
{
    const float* inp = in + (size_t)bz * K * N;
    ushort* outp = out + (size_t)bz * K * N;
    ushort (*T)[132] = (ushort(*)[132])smem;
    const int k0 = by * 64, n0 = bx * 128;
    {
        const int rr = t >> 5;           // 0..7
        const int c4 = (t & 31) * 4;     // 0..124
        float4 v[8];
#pragma unroll
        for (int i = 0; i < 8; ++i)      // all 8 loads issued before any use
            v[i] = *(const float4*)(inp + (size_t)(k0 + rr + i * 8) * N + n0 + c4);
#pragma unroll
        for (int i = 0; i < 8; ++i) {
            const int row = rr + i * 8;
            ushort4 o;
            o.x = f2b(v[i].x); o.y = f2b(v[i].y); o.z = f2b(v[i].z); o.w = f2b(v[i].w);
            *(ushort4*)&T[row][c4 ^ ((row >> 3) << 2)] = o;
        }
    }
    __syncthreads();
    {
        const int g  = t >> 3;           // 0..31: output-row group
        const int kg = t & 7;            // 0..7 : 8-k chunk within the 64-k tile
#pragma unroll
        for (int p = 0; p < 4; ++p) {
            const int nn = p * 32 + g;   // 0..127
            const int nsw = nn ^ (kg << 2);
            const int gn = n0 + nn;
            int np;
            if (PAIR_H > 0)
                np = (gn < PAIR_H) ? ((gn >> 4) * 32 + (gn & 15))
                                   : (((gn - PAIR_H) >> 4) * 32 + 16 + ((gn - PAIR_H) & 15));
            else
                np = gn;
            short8 o;
#pragma unroll
            for (int j = 0; j < 8; ++j) o[j] = (short)T[kg * 8 + j][nsw];
            *(short8*)(outp + (size_t)np * K + k0 + kg * 8) = o;
        }
    }
}

// ---------------- L1: router + sgw transpose ----------------
__global__ __launch_bounds__(256) void prep1(
    const float* __restrict__ x, const float* __restrict__ gw,
    const float* __restrict__ gb, const float* __restrict__ sgw,
    ushort* __restrict__ xb, int* __restrict__ topk_idx,
    float* __restrict__ topk_w, ushort* __restrict__ sgw_t)
{
    __shared__ __align__(16) char smem[16896];   // union: T[64][132] bf16 / router 5.25 KB
    const int b = blockIdx.x;
    const int t = threadIdx.x;
    if (b < 256)                          // sgw: (bx 0..15, by 0..15)
        transp_body<C_DIM, 2 * HS_SH, HS_SH>(sgw, sgw_t, b & 15, b >> 4, 0, t, smem);
    else                                  // router: 2048 token blocks
        router_body(b - 256, t, x, gw, gb, xb, topk_idx, topk_w, smem);
}

// ---------------- Routing meta: count + scan + scatter, one block ----------------
__global__ __launch_bounds__(1024) void route_build(
    const int* __restrict__ topk_idx, const float* __restrict__ topk_w,
    int* __restrict__ offsets, int* __restrict__ perm_token,
    float* __restrict__ perm_w, int* __restrict__ inv_slot)
{
    __shared__ int cnt[E_NUM];
    __shared__ int off_s[E_NUM + 1];
    const int t = threadIdx.x;
    if (t < E_NUM) cnt[t] = 0;
    __syncthreads();
    int myidx[8];
#pragma unroll
    for (int j = 0; j < 8; ++j) {
        const int i = t * 8 + j;
        myidx[j] = topk_idx[i];
        atomicAdd(&cnt[myidx[j]], 1);
    }
    __syncthreads();
    if (t == 0) {
        int a = 0;
        for (int e2 = 0; e2 < E_NUM; ++e2) { off_s[e2] = a; a += cnt[e2]; }
        off_s[E_NUM] = a;
    }
    __syncthreads();
    if (t < E_NUM) cnt[t] = off_s[t];          // reuse as cursor
    if (t <= E_NUM) offsets[t] = off_s[t];
    __syncthreads();
#pragma unroll
    for (int j = 0; j < 8; ++j) {
        const int i = t * 8 + j;
        const int pos = atomicAdd(&cnt[myidx[j]], 1);
        perm_token[pos] = i >> 2;
        perm_w[pos] = topk_w[i];
        inv_slot[i] = pos;
    }
}

// ---------------- bf16 MFMA GEMM body, 128x128 tile, m97 structure ----------------
// Takes explicit (bx, by) so it can live at any position in a flat-decoded grid.
template<int K, int NP, bool EXPERT>
__device__ __forceinline__ void swiglu_body(
    const ushort* __restrict__ Ab, const ushort* __restrict__ Bt,
    ushort* __restrict__ Out, const int* __restrict__ offsets,
    const int* __restrict__ perm_tok, int eidx, int bx, int by, ushort* S)
{
    constexpr int H = NP / 2;
    int base = 0, cnt = N_TOK;
    const ushort* Bp = Bt;
    if (EXPERT) {
        base = offsets[eidx]; cnt = offsets[eidx + 1] - base;
        Bp = Bt + (size_t)eidx * NP * K;
    }
    const int n0 = bx * 128;
    const int m0 = by * 128;
    if (m0 >= cnt) return;
    ushort* O = Out + (size_t)base * H;

    ushort* As = S;
    ushort* Bs = S + 128 * 64;

    const int t = threadIdx.x;
    const int lane = t & 63, wave = t >> 6;
    const int wr = wave >> 1, wc = wave & 1;
    const int quad = lane >> 4, l16 = lane & 15;
    const int srow = lane >> 3;                  // 0..7 within the wave's 8-row group
    const int schunk = (lane & 7) ^ srow;        // swizzled logical 16B-chunk

    f32x4 acc[4][4];
#pragma unroll
    for (int i = 0; i < 4; ++i)
#pragma unroll
        for (int j = 0; j < 4; ++j) acc[i][j] = (f32x4){0.f, 0.f, 0.f, 0.f};

    const ushort* AgI[4];
#pragma unroll
    for (int i = 0; i < 4; ++i) {
        int ar = m0 + wave * 8 + srow + i * 32;
        if (EXPERT) {
            ar = ar < cnt ? ar : 0;
            AgI[i] = Ab + (size_t)perm_tok[base + ar] * K + schunk * 8;
        } else {
            AgI[i] = Ab + (size_t)(base + ar) * K + schunk * 8;
        }
    }
    const ushort* Bg = Bp + (size_t)(n0 + wave * 8 + srow) * K + schunk * 8;

    for (int k0 = 0; k0 < K; k0 += 64) {
        __syncthreads();                         // prev tile reads done
#pragma unroll
        for (int i = 0; i < 4; ++i) {
            glds16(AgI[i] + k0, As + (wave * 8 + i * 32) * 64);
            glds16(Bg + (size_t)(i * 32) * K + k0, Bs + (wave * 8 + i * 32) * 64);
        }
        __syncthreads();                         // vmcnt(0) drain -> DMA visible
#pragma unroll
        for (int ks = 0; ks < 2; ++ks) {
            const int coff = (((ks * 4 + quad) ^ (l16 & 7)) << 3);
            short8 af[4], bfr[4];
#pragma unroll
            for (int i = 0; i < 4; ++i) {
                af[i]  = *(const short8*)(As + (wr * 64 + i * 16 + l16) * 64 + coff);
                bfr[i] = *(const short8*)(Bs + (wc * 64 + i * 16 + l16) * 64 + coff);
            }
#pragma unroll
            for (int tm = 0; tm < 4; ++tm)
#pragma unroll
                for (int tn = 0; tn < 4; ++tn)
                    acc[tm][tn] = __builtin_amdgcn_mfma_f32_16x16x32_bf16(
                        af[tm], bfr[tn], acc[tm][tn], 0, 0, 0);
        }
    }

    // Epilogue: SwiGLU pair-combine (tn even=y, odd=g), LDS transpose, 16B stores
    __syncthreads();
#pragma unroll
    for (int tm = 0; tm < 4; ++tm)
#pragma unroll
        for (int p = 0; p < 2; ++p)
#pragma unroll
            for (int r = 0; r < 4; ++r) {
                const int ml = wr * 64 + tm * 16 + quad * 4 + r;
                const int hl = wc * 32 + p * 16 + l16;
                const float y = acc[tm][2 * p][r];
                const float g = acc[tm][2 * p + 1][r];
                S[ml * 72 + hl] = f2b(silu_f(g) * y);    // view as [128][72]
            }
    __syncthreads();
#pragma unroll
    for (int i = 0; i < 4; ++i) {
        const int c = t + i * 256;
        const int row = c >> 3, col = (c & 7) * 8;
        if (m0 + row < cnt)
            *(float4*)(O + (size_t)(m0 + row) * H + (n0 >> 1) + col) =
                *(const float4*)(S + row * 72 + col);
    }
}

template<int K, bool EXPERT>
__device__ __forceinline__ void down_body(
    const ushort* __restrict__ Ab, const ushort* __restrict__ Bt,
    float* __restrict__ Out, const int* __restrict__ offsets,
    const float* __restrict__ perm_w, int eidx, int bx, int by, ushort* S)
{
    int base = 0, cnt = N_TOK;
    const ushort* Bp = Bt;
    if (EXPERT) {
        base = offsets[eidx]; cnt = offsets[eidx + 1] - base;
        Bp = Bt + (size_t)eidx * C_DIM * K;
    }
    const int m0 = by * 128;
    if (m0 >= cnt) return;
    const int n0 = bx * 128;
    const ushort* Ap = Ab + (size_t)base * K;

    ushort* As = S;
    ushort* Bs = S + 128 * 64;

    const int t = threadIdx.x;
    const int lane = t & 63, wave = t >> 6;
    const int wr = wave >> 1, wc = wave & 1;
    const int quad = lane >> 4, l16 = lane & 15;
    const int srow = lane >> 3;
    const int schunk = (lane & 7) ^ srow;

    f32x4 acc[4][4];
#pragma unroll
    for (int i = 0; i < 4; ++i)
#pragma unroll
        for (int j = 0; j < 4; ++j) acc[i][j] = (f32x4){0.f, 0.f, 0.f, 0.f};

    const ushort* Ag = Ap + (size_t)(m0 + wave * 8 + srow) * K + schunk * 8;
    const ushort* Bg = Bp + (size_t)(n0 + wave * 8 + srow) * K + schunk * 8;

    for (int k0 = 0; k0 < K; k0 += 64) {
        __syncthreads();
#pragma unroll
        for (int i = 0; i < 4; ++i) {
            glds16(Ag + (size_t)(i * 32) * K + k0, As + (wave * 8 + i * 32) * 64);
            glds16(Bg + (size_t)(i * 32) * K + k0, Bs + (wave * 8 + i * 32) * 64);
        }
        __syncthreads();
#pragma unroll
        for (int ks = 0; ks < 2; ++ks) {
            const int coff = (((ks * 4 + quad) ^ (l16 & 7)) << 3);
            short8 af[4], bfr[4];
#pragma unroll
            for (int i = 0; i < 4; ++i) {
                af[i]  = *(const short8*)(As + (wr * 64 + i * 16 + l16) * 64 + coff);
                bfr[i] = *(const short8*)(Bs + (wc * 64 + i * 16 + l16) * 64 + coff);
            }
#pragma unroll
            for (int tm = 0; tm < 4; ++tm)
#pragma unroll
                for (int tn = 0; tn < 4; ++tn)
                    acc[tm][tn] = __builtin_amdgcn_mfma_f32_16x16x32_bf16(
                        af[tm], bfr[tn], acc[tm][tn], 0, 0, 0);
        }
    }

#pragma unroll
    for (int tm = 0; tm < 4; ++tm)
#pragma unroll
        for (int r = 0; r < 4; ++r) {
            const int grow = m0 + wr * 64 + tm * 16 + quad * 4 + r;
            if (EXPERT) {
                if (grow < cnt) {
                    const float w = perm_w[base + grow];
#pragma unroll
                    for (int tn = 0; tn < 4; ++tn) {
                        const int col = n0 + wc * 64 + tn * 16 + l16;
                        Out[(size_t)(base + grow) * C_DIM + col] = w * acc[tm][tn][r];
                    }
                }
            } else {
#pragma unroll
                for (int tn = 0; tn < 4; ++tn) {
                    const int col = n0 + wc * 64 + tn * 16 + l16;
                    Out[(size_t)grow * C_DIM + col] = acc[tm][tn][r];
                }
            }
        }
}

// ---------------- L3: shared swiglu + egw transpose + sdw transpose ----------------
// shared swiglu needs xb,sgw_t (L1); transposes independent. egw's ~190 MB of
// memory work overlaps the shared GEMM's MFMA phases.
__global__ __launch_bounds__(256, 3) void phase3(
    const ushort* __restrict__ xb, const ushort* __restrict__ sgw_t,
    ushort* __restrict__ Hs_b, const float* __restrict__ egw,
    const float* __restrict__ sdw, ushort* __restrict__ egw_t,
    ushort* __restrict__ sdw_t)
{
    __shared__ __align__(16) ushort S[2 * 128 * 64];   // 32 KB union
    const int b = blockIdx.x;
    const int t = threadIdx.x;
    if (b < 256) {                        // shared swiglu: (bx 0..15, by 0..15)
        swiglu_body<C_DIM, 2 * HS_SH, false>(xb, sgw_t, Hs_b, nullptr, nullptr, 0,
                                             b & 15, b >> 4, S);
    } else if (b < 4352) {                // egw transp: (bx 0..7, by 0..15, bz 0..31)
        const int r = b - 256;
        transp_body<C_DIM, 2 * H_EXP, H_EXP>(egw, egw_t, r & 7, (r >> 3) & 15, r >> 7,
                                             t, (char*)S);
    } else {                              // sdw transp: (bx 0..7, by 0..15)
        const int r = b - 4352;
        transp_body<HS_SH, C_DIM, 0>(sdw, sdw_t, r & 7, r >> 3, 0, t, (char*)S);
    }
}

// ---------------- L4: expert swiglu + shared down + edw transpose ----------------
// expert swiglu needs egw_t (L3), offsets/perm (L2); shared down needs Hs_b,sdw_t (L3);
// edw transpose independent (consumed by L5).
__global__ __launch_bounds__(256, 3) void phase4(
    const ushort* __restrict__ xb, const ushort* __restrict__ egw_t,
    ushort* __restrict__ He_b, const int* __restrict__ offsets,
    const int* __restrict__ perm_tok, const ushort* __restrict__ Hs_b,
    const ushort* __restrict__ sdw_t, float* __restrict__ out,
    const float* __restrict__ edw, ushort* __restrict__ edw_t)
{
    __shared__ __align__(16) ushort S[2 * 128 * 64];
    const int b = blockIdx.x;
    const int t = threadIdx.x;
    if (b < 4096) {                       // expert swiglu: e = b>>7, (bx 0..7, by 0..15)
        const int r = b & 127;
        swiglu_body<C_DIM, 2 * H_EXP, true>(xb, egw_t, He_b, offsets, perm_tok,
                                            b >> 7, r & 7, r >> 3, S);
    } else if (b < 4224) {                // shared down: (bx 0..7, by 0..15)
        const int r = b - 4096;
        down_body<HS_SH, false>(Hs_b, sdw_t, out, nullptr, nullptr, 0,
                                r & 7, r >> 3, S);
    } else {                              // edw transp: (bx 0..7, by 0..7, bz 0..31)
        const int r = b - 4224;
        transp_body<H_EXP, C_DIM, 0>(edw, edw_t, r & 7, (r >> 3) & 7, r >> 6,
                                     t, (char*)S);
    }
}

// ---------------- L5: expert down ----------------
__global__ __launch_bounds__(256, 3) void phase5(
    const ushort* __restrict__ He_b, const ushort* __restrict__ edw_t,
    float* __restrict__ Ye, const int* __restrict__ offsets,
    const float* __restrict__ perm_w)
{
    __shared__ __align__(16) ushort S[2 * 128 * 64];
    const int b = blockIdx.x;             // e = b>>7, (bx 0..7, by 0..15)
    const int r = b & 127;
    down_body<H_EXP, true>(He_b, edw_t, Ye, offsets, perm_w, b >> 7,
                           r & 7, r >> 3, S);
}

// out[token] += sum_k Ye[slot_k(token)]   (shared result already in out)
__global__ __launch_bounds__(256) void combine_kernel(
    const float* __restrict__ Ye, const int* __restrict__ inv_slot,
    float* __restrict__ Out)
{
    const int tok = blockIdx.x;
    __shared__ int s4[TOPKK];
    if (threadIdx.x < TOPKK) s4[threadIdx.x] = inv_slot[tok * TOPKK + threadIdx.x];
    __syncthreads();
    const int c = threadIdx.x * 4;
    float4 acc = *(const float4*)(Out + (size_t)tok * C_DIM + c);
#pragma unroll
    for (int k = 0; k < TOPKK; ++k) {
        float4 v = *(const float4*)(Ye + (size_t)s4[k] * C_DIM + c);
        acc.x += v.x; acc.y += v.y; acc.z += v.z; acc.w += v.w;
    }
    *(float4*)(Out + (size_t)tok * C_DIM + c) = acc;
}

extern "C" void kernel_launch(void* const* d_in, const int* in_sizes, int n_in,
                              void* d_out, int out_size, void* d_ws, size_t ws_size,
                              hipStream_t stream)
{
    const float* x   = (const float*)d_in[0];
    const float* gw  = (const float*)d_in[1];
    const float* gb  = (const float*)d_in[2];
    const float* sgw = (const float*)d_in[3];
    const float* sdw = (const float*)d_in[4];
    const float* egw = (const float*)d_in[5];
    const float* edw = (const float*)d_in[6];
    float* out = (float*)d_out;

    char* ws = (char*)d_ws;
    size_t off = 0;
    auto alloc = [&](size_t bytes) -> void* {
        void* p = ws + off;
        off = (off + bytes + 255) & ~(size_t)255;
        return p;
    };
    int*    topk_idx = (int*)   alloc((size_t)NSLOT * sizeof(int));
    float*  topk_w   = (float*) alloc((size_t)NSLOT * sizeof(float));
    int*    offsets  = (int*)   alloc((E_NUM + 1) * sizeof(int));
    int*    perm_tok = (int*)   alloc((size_t)NSLOT * sizeof(int));
    float*  perm_w   = (float*) alloc((size_t)NSLOT * sizeof(float));
    int*    inv_slot = (int*)   alloc((size_t)NSLOT * sizeof(int));
    ushort* xb       = (ushort*)alloc((size_t)N_TOK * C_DIM * 2);
    ushort* sgw_t    = (ushort*)alloc((size_t)C_DIM * 2 * HS_SH * 2);
    ushort* sdw_t    = (ushort*)alloc((size_t)HS_SH * C_DIM * 2);
    ushort* egw_t    = (ushort*)alloc((size_t)E_NUM * C_DIM * 2 * H_EXP * 2);
    ushort* edw_t    = (ushort*)alloc((size_t)E_NUM * H_EXP * C_DIM * 2);
    ushort* Hs_b     = (ushort*)alloc((size_t)N_TOK * HS_SH * 2);
    ushort* He_b     = (ushort*)alloc((size_t)(NSLOT + 128) * H_EXP * 2);
    float*  Ye       = (float*) alloc((size_t)(NSLOT + 128) * C_DIM * sizeof(float));
    (void)ws_size; (void)in_sizes; (void)n_in; (void)out_size;

    // L1: sgw transpose (256) + router (2048)
    prep1<<<2304, 256, 0, stream>>>(x, gw, gb, sgw, xb, topk_idx, topk_w, sgw_t);
    // L2: routing metadata
    route_build<<<1, 1024, 0, stream>>>(topk_idx, topk_w, offsets, perm_tok, perm_w, inv_slot);
    // L3: shared swiglu (256) + egw transpose (4096) + sdw transpose (128)
    phase3<<<4480, 256, 0, stream>>>(xb, sgw_t, Hs_b, egw, sdw, egw_t, sdw_t);
    // L4: expert swiglu (4096) + shared down (128) + edw transpose (2048)
    phase4<<<6272, 256, 0, stream>>>(xb, egw_t, He_b, offsets, perm_tok,
                                     Hs_b, sdw_t, out, edw, edw_t);
    // L5: expert down
    phase5<<<4096, 256, 0, stream>>>(He_b, edw_t, Ye, offsets, perm_w);
    // L6: combine
    combine_kernel<<<N_TOK, 256, 0, stream>>>(Ye, inv_slot, out);
}